// Round 6
// baseline (124.618 us; speedup 1.0000x reference)
//
#include <hip/hip_runtime.h>
#include <hip/hip_bf16.h>

#define NDIM 128
#define BDIM 131072
#define NMZI 8128                       // 128*127/2
#define NCHUNK 8
#define CSTEP (NMZI / NCHUNK)           // 1016 steps per chunk
#define NJG 8                           // j-groups per block (scan groups)
#define NCOL 32                         // columns per block
#define NLOC 16                         // max local scan length
static constexpr float CC = 0.70710678118654752440f;  // sqrt(0.5)

typedef __attribute__((ext_vector_type(8))) short bf16x8;
typedef __attribute__((ext_vector_type(4))) float f32x4;

// Static device scratch (d_ws size unknown -> don't touch it)
__device__ __align__(16) float2         g_V[NCHUNK * NDIM * NDIM];  // chunk partial unitaries
__device__ __align__(16) float2         g_W[4 * NDIM * NDIM];       // compose level 1
__device__ __align__(16) float2         g_Y[2 * NDIM * NDIM];       // compose level 2
// Packed K=256 table for real-output GEMM: kg2<16 -> Ur[k=kg2*8+e][n]; kg2>=16 -> -Ui
__device__ __align__(16) unsigned short g_TB[32 * NDIM * 8];        // 64 KB
// Separate tables for the (unlikely) complex-interleaved output mode
__device__ __align__(16) unsigned short g_Ur[16 * NDIM * 8];
__device__ __align__(16) unsigned short g_Ui[16 * NDIM * 8];

__device__ inline unsigned short f2bf(float f) {
    union { __hip_bfloat16 h; unsigned short u; } cv;
    cv.h = __float2bfloat16(f);
    return cv.u;
}

// ---------------- K2: build chunk partial unitaries (affine-scan) ----------------
__global__ __launch_bounds__(256) void build_scan(const float* __restrict__ mzi) {
    __shared__ float2 Usm[NDIM][NCOL];        // 32 KB
    __shared__ float4 phs[CSTEP];             // 16.25 KB
    __shared__ float4 comp[NJG][NCOL];        // 4 KB
    const int tid   = threadIdx.x;
    const int c     = tid & 31;
    const int g     = tid >> 5;
    const int col0  = blockIdx.x * NCOL;
    const int chunk = blockIdx.y;
    const int s0 = chunk * CSTEP, s1 = s0 + CSTEP;

    for (int k = g; k < NDIM; k += NJG)
        Usm[k][c] = make_float2((k == col0 + c) ? 1.f : 0.f, 0.f);
    const float2* mzp = (const float2*)mzi;   // (theta, phi) pairs
    for (int t = tid; t < CSTEP; t += 256) {
        const float2 mz = mzp[s0 + t];
        float sp, cp, st, ct;
        sincosf(mz.y, &sp, &cp);              // phi
        sincosf(mz.x, &st, &ct);              // theta
        phs[t] = make_float4(cp, sp, CC * ct, CC * st);
    }
    __syncthreads();

    int i = 0, base = 0;
    while (base + (NDIM - 1 - i) <= s0) { base += NDIM - 1 - i; ++i; }

    int s = s0;
    while (s < s1) {
        const int cnt  = NDIM - 1 - i;
        const int jA   = i + 1 + (s - base);
        const int L    = min(s1, base + cnt) - s;
        const int nloc = (L + NJG - 1) >> 3;
        const int myBeg = g * nloc;
        const int myN   = max(0, min(nloc, L - myBeg));
        const int pbase = s - s0;

        const float2 r0 = Usm[i][c];          // read BEFORE barrier

        float2 treg[NLOC];
        float2 qth[NLOC];
        float  A = 1.f;
        float2 Bc = make_float2(0.f, 0.f);
        #pragma unroll
        for (int kk = 0; kk < NLOC; ++kk) {
            if (kk < myN) {
                const int off = myBeg + kk;
                const float4 q  = phs[pbase + off];
                const float2 rj = Usm[jA + off][c];
                const float tr = fmaf(q.x, rj.x, -q.y * rj.y);
                const float ti = fmaf(q.x, rj.y,  q.y * rj.x);
                treg[kk] = make_float2(tr, ti);
                qth[kk]  = make_float2(q.z, q.w);
                Bc.x = CC * (Bc.x + tr);
                Bc.y = CC * (Bc.y + ti);
                A *= CC;
            }
        }
        comp[g][c] = make_float4(A, Bc.x, Bc.y, 0.f);
        __syncthreads();

        float2 r = r0;
        for (int h = 0; h < g; ++h) {
            const float4 cm = comp[h][c];
            r.x = fmaf(cm.x, r.x, cm.y);
            r.y = fmaf(cm.x, r.y, cm.z);
        }

        #pragma unroll
        for (int kk = 0; kk < NLOC; ++kk) {
            if (kk < myN) {
                const float2 t = treg[kk];
                const float2 q = qth[kk];
                const float dr = r.x - t.x, di = r.y - t.y;
                const float njx = fmaf(q.x, dr, -q.y * di);
                const float njy = fmaf(q.x, di,  q.y * dr);
                Usm[jA + myBeg + kk][c] = make_float2(njx, njy);
                r.x = CC * (r.x + t.x);
                r.y = CC * (r.y + t.y);
            }
        }
        if (myN > 0 && (myBeg + myN == L))
            Usm[i][c] = r;
        __syncthreads();

        s += L;
        if (s == base + cnt) { base += cnt; ++i; }
    }

    float2* Vp = g_V + chunk * NDIM * NDIM;
    for (int k = g; k < NDIM; k += NJG)
        Vp[k * NDIM + col0 + c] = Usm[k][c];
}

// ---------------- K3: compose tree level ----------------
__global__ __launch_bounds__(128) void compose(int level) {
    const int p = blockIdx.y, n = blockIdx.x, m = threadIdx.x;
    const float2* A; const float2* B; float2* Cout;
    if (level == 0) {
        A = g_V + (2 * p + 1) * NDIM * NDIM;
        B = g_V + (2 * p) * NDIM * NDIM;
        Cout = g_W + p * NDIM * NDIM;
    } else {
        A = g_W + (2 * p + 1) * NDIM * NDIM;
        B = g_W + (2 * p) * NDIM * NDIM;
        Cout = g_Y + p * NDIM * NDIM;
    }
    __shared__ float2 arow[NDIM];
    arow[m] = A[n * NDIM + m];
    __syncthreads();
    float cr = 0.f, ci = 0.f;
    #pragma unroll 8
    for (int k = 0; k < NDIM; ++k) {
        const float2 b = B[k * NDIM + m];
        const float2 a = arow[k];
        cr = fmaf(a.x, b.x, fmaf(-a.y, b.y, cr));
        ci = fmaf(a.x, b.y, fmaf( a.y, b.x, ci));
    }
    Cout[n * NDIM + m] = make_float2(cr, ci);
}

// ---------------- K4: final compose U = Y1*Y0, diag, emit packed bf16 ----------------
__global__ __launch_bounds__(128) void compose_final(const float* __restrict__ oph) {
    const int n = blockIdx.x, m = threadIdx.x;
    const float2* A = g_Y + NDIM * NDIM;   // Y1 (left)
    const float2* B = g_Y;                 // Y0 (right)
    __shared__ float2 arow[NDIM];
    arow[m] = A[n * NDIM + m];
    __syncthreads();
    float cr = 0.f, ci = 0.f;
    #pragma unroll 8
    for (int k = 0; k < NDIM; ++k) {
        const float2 b = B[k * NDIM + m];
        const float2 a = arow[k];
        cr = fmaf(a.x, b.x, fmaf(-a.y, b.y, cr));
        ci = fmaf(a.x, b.y, fmaf( a.y, b.x, ci));
    }
    float ds, dc;
    sincosf(oph[n], &ds, &dc);
    const float vr = fmaf(cr, dc, -ci * ds);
    const float vi = fmaf(cr, ds,  ci * dc);
    const int kg = m >> 3, e = m & 7;
    g_TB[(kg * NDIM + n) * 8 + e]        = f2bf(vr);
    g_TB[((16 + kg) * NDIM + n) * 8 + e] = f2bf(-vi);
    g_Ur[(kg * NDIM + n) * 8 + e] = f2bf(vr);
    g_Ui[(kg * NDIM + n) * 8 + e] = f2bf(vi);
}

// ---------------- K5a: real-output GEMM (out_size == B*N, f32 real part) ----------------
// 1024 blocks x 256 threads (4 waves); wave does 2 tiles of 16 b-rows.
// Packed [Ur | -Ui] (K=256) in LDS. MFMA operand-swapped (table=A, x=B):
// lane's 4 D regs = 4 consecutive n of its own b-row -> one 16B store.
// All buffers static-named (rule #20: no runtime-indexed arrays / array
// pointers -> keep everything in VGPRs, no scratch).
#define LOAD_TILE(Lb, rowbase)                                                  \
    {                                                                           \
        const float* xrp_ = xr + (size_t)(rowbase) * NDIM;                      \
        const float* xip_ = xi + (size_t)(rowbase) * NDIM;                      \
        _Pragma("unroll")                                                       \
        for (int kc_ = 0; kc_ < 4; ++kc_) {                                     \
            const int k0_ = kc_ * 32 + kg4 * 8;                                 \
            Lb[kc_ * 2]     = *(const float4*)(xrp_ + k0_);                     \
            Lb[kc_ * 2 + 1] = *(const float4*)(xrp_ + k0_ + 4);                 \
            Lb[8 + kc_ * 2]     = *(const float4*)(xip_ + k0_);                 \
            Lb[8 + kc_ * 2 + 1] = *(const float4*)(xip_ + k0_ + 4);             \
        }                                                                       \
    }

#define CONVERT_TILE(Lb, fxb)                                                   \
    {                                                                           \
        _Pragma("unroll")                                                       \
        for (int h_ = 0; h_ < 8; ++h_) {                                        \
            const float4 lo_ = Lb[h_ * 2];                                      \
            const float4 hi_ = Lb[h_ * 2 + 1];                                  \
            bf16x8 v_;                                                          \
            v_[0] = (short)f2bf(lo_.x); v_[1] = (short)f2bf(lo_.y);             \
            v_[2] = (short)f2bf(lo_.z); v_[3] = (short)f2bf(lo_.w);             \
            v_[4] = (short)f2bf(hi_.x); v_[5] = (short)f2bf(hi_.y);             \
            v_[6] = (short)f2bf(hi_.z); v_[7] = (short)f2bf(hi_.w);             \
            fxb[h_] = v_;                                                       \
        }                                                                       \
    }

#define COMPUTE_STORE(fxb, rowbase)                                             \
    {                                                                           \
        const size_t orow_ = (size_t)(rowbase) * NDIM;                          \
        _Pragma("unroll")                                                       \
        for (int nt_ = 0; nt_ < 8; ++nt_) {                                     \
            f32x4 a0_ = {0.f, 0.f, 0.f, 0.f};                                   \
            f32x4 a1_ = {0.f, 0.f, 0.f, 0.f};                                   \
            _Pragma("unroll")                                                   \
            for (int kc_ = 0; kc_ < 4; ++kc_) {                                 \
                const bf16x8 tf_ = smT[(kc_ * 4 + kg4) * NDIM + nt_ * 16 + r15];\
                a0_ = __builtin_amdgcn_mfma_f32_16x16x32_bf16(tf_, fxb[kc_], a0_, 0, 0, 0); \
            }                                                                   \
            _Pragma("unroll")                                                   \
            for (int kc_ = 4; kc_ < 8; ++kc_) {                                 \
                const bf16x8 tf_ = smT[(kc_ * 4 + kg4) * NDIM + nt_ * 16 + r15];\
                a1_ = __builtin_amdgcn_mfma_f32_16x16x32_bf16(tf_, fxb[kc_], a1_, 0, 0, 0); \
            }                                                                   \
            const f32x4 s_ = a0_ + a1_;                                         \
            *(float4*)(out + orow_ + nt_ * 16 + kg4 * 4) =                      \
                make_float4(s_[0], s_[1], s_[2], s_[3]);                        \
        }                                                                       \
    }

__global__ __launch_bounds__(256) void cmatmul0(const float* __restrict__ xr,
                                                const float* __restrict__ xi,
                                                float* __restrict__ out) {
    __shared__ bf16x8 smT[32 * NDIM];     // 64 KB
    const int tid  = threadIdx.x;
    const int lane = tid & 63;
    const int w    = tid >> 6;
    const int r15  = lane & 15;
    const int kg4  = lane >> 4;
    const int row0 = blockIdx.x * 128 + w * 16 + r15;   // tile-0 b-row of this lane

    // issue tile-0 x loads first (overlap with table staging)
    float4 L0[16];
    LOAD_TILE(L0, row0)

    const bf16x8* gT = (const bf16x8*)g_TB;
    for (int t = tid; t < 32 * NDIM; t += 256) smT[t] = gT[t];
    __syncthreads();

    // tile 0 fragments; then issue tile-1 loads so they land under tile-0 MFMAs
    bf16x8 fx0[8];
    CONVERT_TILE(L0, fx0)
    float4 L1[16];
    LOAD_TILE(L1, row0 + 64)

    COMPUTE_STORE(fx0, row0)

    bf16x8 fx1[8];
    CONVERT_TILE(L1, fx1)
    COMPUTE_STORE(fx1, row0 + 64)
}

// ---------------- K5b: complex-output fallback (bf16 re,im pairs) ----------------
__global__ __launch_bounds__(256) void cmatmul1(const float* __restrict__ xr,
                                                const float* __restrict__ xi,
                                                ushort2* __restrict__ outp) {
    const int lane  = threadIdx.x & 63;
    const int w     = threadIdx.x >> 6;
    const int btile = blockIdx.x * 64 + w * 16;
    const int r15   = lane & 15;
    const int kg4   = lane >> 4;
    const int bload = btile + r15;

    const bf16x8* Ur = (const bf16x8*)g_Ur;
    const bf16x8* Ui = (const bf16x8*)g_Ui;
    const float* xrp = xr + (size_t)bload * NDIM;
    const float* xip = xi + (size_t)bload * NDIM;

    bf16x8 ar[4], ai[4], ain[4];
    #pragma unroll
    for (int kc = 0; kc < 4; ++kc) {
        const int k0 = kc * 32 + kg4 * 8;
        float4 rlo = *(const float4*)(xrp + k0);
        float4 rhi = *(const float4*)(xrp + k0 + 4);
        float4 ilo = *(const float4*)(xip + k0);
        float4 ihi = *(const float4*)(xip + k0 + 4);
        bf16x8 vr, vi, vn;
        vr[0] = (short)f2bf(rlo.x); vr[1] = (short)f2bf(rlo.y);
        vr[2] = (short)f2bf(rlo.z); vr[3] = (short)f2bf(rlo.w);
        vr[4] = (short)f2bf(rhi.x); vr[5] = (short)f2bf(rhi.y);
        vr[6] = (short)f2bf(rhi.z); vr[7] = (short)f2bf(rhi.w);
        vi[0] = (short)f2bf(ilo.x); vi[1] = (short)f2bf(ilo.y);
        vi[2] = (short)f2bf(ilo.z); vi[3] = (short)f2bf(ilo.w);
        vi[4] = (short)f2bf(ihi.x); vi[5] = (short)f2bf(ihi.y);
        vi[6] = (short)f2bf(ihi.z); vi[7] = (short)f2bf(ihi.w);
        #pragma unroll
        for (int e = 0; e < 8; ++e) vn[e] = (short)(vi[e] ^ 0x8000);
        ar[kc] = vr; ai[kc] = vi; ain[kc] = vn;
    }

    #pragma unroll
    for (int nt = 0; nt < 8; ++nt) {
        f32x4 accR = {0.f, 0.f, 0.f, 0.f};
        f32x4 accI = {0.f, 0.f, 0.f, 0.f};
        #pragma unroll
        for (int kc = 0; kc < 4; ++kc) {
            const int kg = kc * 4 + kg4;
            bf16x8 br = Ur[kg * NDIM + nt * 16 + r15];
            bf16x8 bi = Ui[kg * NDIM + nt * 16 + r15];
            accR = __builtin_amdgcn_mfma_f32_16x16x32_bf16(ar[kc],  br, accR, 0, 0, 0);
            accR = __builtin_amdgcn_mfma_f32_16x16x32_bf16(ain[kc], bi, accR, 0, 0, 0);
            accI = __builtin_amdgcn_mfma_f32_16x16x32_bf16(ar[kc],  bi, accI, 0, 0, 0);
            accI = __builtin_amdgcn_mfma_f32_16x16x32_bf16(ai[kc],  br, accI, 0, 0, 0);
        }
        const int n    = nt * 16 + r15;
        const int brow = btile + kg4 * 4;
        #pragma unroll
        for (int r = 0; r < 4; ++r)
            outp[(size_t)(brow + r) * NDIM + n] = make_ushort2(f2bf(accR[r]), f2bf(accI[r]));
    }
}

extern "C" void kernel_launch(void* const* d_in, const int* in_sizes, int n_in,
                              void* d_out, int out_size, void* d_ws, size_t ws_size,
                              hipStream_t stream) {
    const float* xr  = (const float*)d_in[0];
    const float* xi  = (const float*)d_in[1];
    const float* mzi = (const float*)d_in[2];
    const float* oph = (const float*)d_in[3];

    build_scan<<<dim3(4, NCHUNK), dim3(256), 0, stream>>>(mzi);
    compose<<<dim3(NDIM, 4), dim3(128), 0, stream>>>(0);
    compose<<<dim3(NDIM, 2), dim3(128), 0, stream>>>(1);
    compose_final<<<dim3(NDIM), dim3(128), 0, stream>>>(oph);
    if (out_size == BDIM * NDIM) {
        cmatmul0<<<dim3(1024), dim3(256), 0, stream>>>(xr, xi, (float*)d_out);
    } else {
        cmatmul1<<<dim3(BDIM / 64), dim3(256), 0, stream>>>(xr, xi, (ushort2*)d_out);
    }
}